// Round 19
// baseline (119.481 us; speedup 1.0000x reference)
//
#include <hip/hip_runtime.h>
#include <hip/hip_fp16.h>
#include <cstdint>

#define NNODES 100000
#define NEDGES 1200000
#define INF 64
#define OUTF 32
#define SCAN_B 256
#define NBUCK ((NNODES + SCAN_B - 1) / SCAN_B)   // 391; bucket b = dst >> 8
#define PCAP 4608                                 // packed slots/bucket
#define SHCAP 576                                 // slots per shard (8 shards/bucket)
#define PADCAP 5632                               // col slots/bucket (8-padded runs)
#define BIN_EPT 16
#define BIN_THREADS (NEDGES / BIN_EPT)            // 75000
#define BIN_BLOCKS ((BIN_THREADS + 255) / 256)    // 293
#define PROJ_NPB 16
#define PROJ_BLOCKS (NNODES / PROJ_NPB)           // 6250 (exact)
#define CUR_PAD 16                                // 64B-padded global cursors
#define WST 66                                    // proj LDS row stride (floats)

// ---- init: sharded cursors + phantom u-rows (row NNODES of h0/h1) ----
__global__ __launch_bounds__(256) void k_initcur(int* __restrict__ gcur,
                                                 uint4* __restrict__ h0,
                                                 uint4* __restrict__ h1) {
    int i = blockIdx.x * 256 + threadIdx.x;
    if (i < NBUCK * 8) gcur[i * CUR_PAD] = (i >> 3) * PCAP + (i & 7) * SHCAP;
    if (i >= 3200 && i < 3204) h0[(size_t)NNODES * 4 + (i - 3200)] = make_uint4(0, 0, 0, 0);
    if (i >= 3204 && i < 3208) h1[(size_t)NNODES * 4 + (i - 3204)] = make_uint4(0, 0, 0, 0);
}

// ---- fused: blocks [0,BIN_BLOCKS) bin edges; rest project h0 = X@W^T ----
// Phase-1 atomicAdd return IS the scatter slot: no second LDS-atomic pass.
__global__ __launch_bounds__(256) void k_binproj(const int4* __restrict__ src4,
                                                 const int4* __restrict__ dst4,
                                                 int* __restrict__ gcur,
                                                 unsigned* __restrict__ packed,
                                                 const float4* __restrict__ feat4,
                                                 const float4* __restrict__ W4,
                                                 __half2* __restrict__ h0_p) {
    __shared__ __align__(16) char smem[12672];
    int tid = threadIdx.x;
    if (blockIdx.x < BIN_BLOCKS) {
        int* cnt = (int*)smem;
        int* base = cnt + NBUCK;
        int shard = blockIdx.x & 7;
        for (int i = tid; i < NBUCK; i += 256) cnt[i] = 0;
        __syncthreads();
        int gid = blockIdx.x * 256 + tid;
        bool act = gid < BIN_THREADS;
        int4 s4[4], d4[4];
        int relv[4][4];
        if (act) {
#pragma unroll
            for (int k = 0; k < 4; ++k) {
                s4[k] = src4[(size_t)gid * 4 + k];
                d4[k] = dst4[(size_t)gid * 4 + k];
                relv[k][0] = atomicAdd(&cnt[d4[k].x >> 8], 1);
                relv[k][1] = atomicAdd(&cnt[d4[k].y >> 8], 1);
                relv[k][2] = atomicAdd(&cnt[d4[k].z >> 8], 1);
                relv[k][3] = atomicAdd(&cnt[d4[k].w >> 8], 1);
            }
        }
        __syncthreads();
        // reservation: shard-private cursor (R17) — cnt needs no reset
        for (int i = tid; i < NBUCK; i += 256) {
            int c = cnt[i];
            base[i] = c ? atomicAdd(&gcur[(i * 8 + shard) * CUR_PAD], c) : 0;
        }
        __syncthreads();
        if (act) {
#pragma unroll
            for (int k = 0; k < 4; ++k) {
                int ss[4] = {s4[k].x, s4[k].y, s4[k].z, s4[k].w};
                int dd[4] = {d4[k].x, d4[k].y, d4[k].z, d4[k].w};
#pragma unroll
                for (int j = 0; j < 4; ++j) {
                    int b = dd[j] >> 8;
                    packed[base[b] + relv[k][j]] =
                        ((unsigned)(dd[j] & 255) << 17) | (unsigned)ss[j];
                }
            }
        }
    } else {
        float (*Ws)[WST] = (float (*)[WST])smem;                    // [32][66]
        float (*Fs)[WST] = (float (*)[WST])(smem + 32 * WST * 4);   // [16][66]
        int node0 = (blockIdx.x - BIN_BLOCKS) * PROJ_NPB;
        for (int i = tid; i < 512; i += 256) {
            float4 w = W4[i];
            int f = i * 4, of = f >> 6, k = f & 63;
            Ws[of][k] = w.x; Ws[of][k + 1] = w.y;
            Ws[of][k + 2] = w.z; Ws[of][k + 3] = w.w;
        }
        {
            int n = node0 + (tid >> 4), q = tid & 15;
            float4 v = feat4[(size_t)n * 16 + q];
            int c = q * 4;
            Fs[tid >> 4][c] = v.x; Fs[tid >> 4][c + 1] = v.y;
            Fs[tid >> 4][c + 2] = v.z; Fs[tid >> 4][c + 3] = v.w;
        }
        __syncthreads();
        int ln = tid >> 4, n = node0 + ln;
        int of0 = (tid & 15) * 2;
        const float2* fp = (const float2*)&Fs[ln][0];
        const float2* w0 = (const float2*)&Ws[of0][0];
        const float2* w1 = (const float2*)&Ws[of0 + 1][0];
        float a0 = 0.0f, a1 = 0.0f;
#pragma unroll
        for (int k2 = 0; k2 < 32; ++k2) {
            float2 f = fp[k2], x = w0[k2], y = w1[k2];
            a0 += f.x * x.x + f.y * x.y;
            a1 += f.x * y.x + f.y * y.y;
        }
        h0_p[(size_t)n * 16 + (tid & 15)] = __floats2half2_rn(a0, a1);
    }
}

// ---- per bucket: walk 8 shard sub-runs; degree (phase-1 rel packed into
//      bits 25..31 of sin_), norm, 8-padded runs, atomic-free scatter, col,
//      rowsd, h0 *= norm epilogue ----
__global__ __launch_bounds__(256) void k_place(const unsigned* __restrict__ packed,
                                               const int* __restrict__ gcur,
                                               int* __restrict__ col,
                                               unsigned* __restrict__ rowsd,
                                               float* __restrict__ norm,
                                               uint4* __restrict__ h0) {
    __shared__ unsigned sin_[PCAP];
    __shared__ int stage[PADCAP];
    __shared__ int deg[SCAN_B];
    __shared__ int rs[SCAN_B];
    __shared__ int moff[SCAN_B];
    __shared__ int slen[8];
    __shared__ int tot;
    int b = blockIdx.x, tid = threadIdx.x;
    int node0 = b * SCAN_B;
    int nn = (NNODES - node0 < SCAN_B) ? (NNODES - node0) : SCAN_B;
    int ebase = b * PCAP;
    int pbase = b * PADCAP;
    if (tid < 8)
        slen[tid] = gcur[(b * 8 + tid) * CUR_PAD] - (b * PCAP + tid * SHCAP);
    deg[tid] = 0;
    __syncthreads();
    for (int s = 0; s < 8; ++s) {
        int len = slen[s];
        for (int i = tid; i < len; i += 256) {
            unsigned pk = packed[ebase + s * SHCAP + i];
            int r = atomicAdd(&deg[pk >> 17], 1);   // packed bits 25+ are 0
            sin_[s * SHCAP + i] = pk | ((unsigned)r << 25);  // rel < 128
        }
    }
    __syncthreads();
    int d = deg[tid];
    int dpad = (d + 7) & ~7;
    rs[tid] = dpad;
    __syncthreads();
    for (int st = 1; st < SCAN_B; st <<= 1) {
        int add = (tid >= st) ? rs[tid - st] : 0;
        __syncthreads();
        rs[tid] += add;
        __syncthreads();
    }
    int myoff = rs[tid] - dpad;  // exclusive scan of padded degrees
    if (tid == SCAN_B - 1) tot = rs[tid];
    float mynorm = rsqrtf(d < 1 ? 1.0f : (float)d);
    if (tid < nn) {
        norm[node0 + tid] = mynorm;
        rowsd[node0 + tid] =
            ((unsigned)((pbase + myoff) >> 3) << 9) | (unsigned)(dpad >> 3);
    }
    moff[tid] = myoff;
    __syncthreads();
    for (int i = tid; i < tot; i += 256) stage[i] = NNODES;  // phantom fill
    __syncthreads();
    for (int s = 0; s < 8; ++s) {
        int len = slen[s];
        for (int i = tid; i < len; i += 256) {
            unsigned pk = sin_[s * SHCAP + i];
            int dl = (pk >> 17) & 0xFF;
            int rel = (int)(pk >> 25);
            stage[moff[dl] + rel] = (int)(pk & 0x1FFFFu);   // no atomic
        }
    }
    __syncthreads();
    for (int i = tid; i < tot; i += 256) col[pbase + i] = stage[i];
    // epilogue: scale this bucket's h0 rows by norm (fp16 in/out, fp32 math)
    if (tid < nn) {
        uint4* hp = h0 + (size_t)(node0 + tid) * 4;
#pragma unroll
        for (int k = 0; k < 4; ++k) {
            uint4 r = hp[k];
            float2 f0 = __half22float2(*(const __half2*)&r.x);
            float2 f1 = __half22float2(*(const __half2*)&r.y);
            float2 f2 = __half22float2(*(const __half2*)&r.z);
            float2 f3 = __half22float2(*(const __half2*)&r.w);
            *(__half2*)&r.x = __floats2half2_rn(mynorm * f0.x, mynorm * f0.y);
            *(__half2*)&r.y = __floats2half2_rn(mynorm * f1.x, mynorm * f1.y);
            *(__half2*)&r.z = __floats2half2_rn(mynorm * f2.x, mynorm * f2.y);
            *(__half2*)&r.w = __floats2half2_rn(mynorm * f3.x, mynorm * f3.y);
            hp[k] = r;
        }
    }
}

// ---- one hop: uout[d] = w(d)*sum_e uin[col[e]]  (+bias) ----
// Runs are 8-padded: exact 8-edge rounds, int4 index loads, no tail.
// u rows: 32 fp16 = 64B; 4 lanes/node, uint4/lane. fp32 accum.
template <bool LAST>
__global__ __launch_bounds__(256) void k_gather(const uint4* __restrict__ uin,
                                                void* __restrict__ uout,
                                                const unsigned* __restrict__ rowsd,
                                                const int4* __restrict__ colv,
                                                const float* __restrict__ norm,
                                                const float4* __restrict__ bias4) {
    int t = blockIdx.x * 256 + threadIdx.x;
    int node = t >> 2;
    if (node >= NNODES) return;
    int lane = t & 3;
    unsigned rd = rowsd[node];
    int c4 = (int)(rd >> 9) * 2;      // int4 index of first col quad
    int n8 = (int)(rd & 511u);        // number of 8-edge rounds
    const uint4* up = uin + lane;
    float4 accA = make_float4(0.f, 0.f, 0.f, 0.f);
    float4 accB = make_float4(0.f, 0.f, 0.f, 0.f);
    auto add = [&](uint4 r) {
        float2 f0 = __half22float2(*(const __half2*)&r.x);
        float2 f1 = __half22float2(*(const __half2*)&r.y);
        float2 f2 = __half22float2(*(const __half2*)&r.z);
        float2 f3 = __half22float2(*(const __half2*)&r.w);
        accA.x += f0.x; accA.y += f0.y; accA.z += f1.x; accA.w += f1.y;
        accB.x += f2.x; accB.y += f2.y; accB.z += f3.x; accB.w += f3.y;
    };
    for (int j = 0; j < n8; ++j) {
        int4 c0 = colv[c4 + j * 2];
        int4 c1 = colv[c4 + j * 2 + 1];
        uint4 r0 = up[(size_t)c0.x * 4];
        uint4 r1 = up[(size_t)c0.y * 4];
        uint4 r2 = up[(size_t)c0.z * 4];
        uint4 r3 = up[(size_t)c0.w * 4];
        uint4 r4 = up[(size_t)c1.x * 4];
        uint4 r5 = up[(size_t)c1.y * 4];
        uint4 r6 = up[(size_t)c1.z * 4];
        uint4 r7 = up[(size_t)c1.w * 4];
        add(r0); add(r1); add(r2); add(r3);
        add(r4); add(r5); add(r6); add(r7);
    }
    float nn = norm[node];
    float w = LAST ? nn : nn * nn;
    accA.x *= w; accA.y *= w; accA.z *= w; accA.w *= w;
    accB.x *= w; accB.y *= w; accB.z *= w; accB.w *= w;
    if (LAST) {
        float4 b0 = bias4[lane * 2], b1 = bias4[lane * 2 + 1];
        accA.x += b0.x; accA.y += b0.y; accA.z += b0.z; accA.w += b0.w;
        accB.x += b1.x; accB.y += b1.y; accB.z += b1.z; accB.w += b1.w;
        float4* o = (float4*)uout;
        o[(size_t)node * 8 + lane * 2]     = accA;
        o[(size_t)node * 8 + lane * 2 + 1] = accB;
    } else {
        uint4 r;
        *(__half2*)&r.x = __floats2half2_rn(accA.x, accA.y);
        *(__half2*)&r.y = __floats2half2_rn(accA.z, accA.w);
        *(__half2*)&r.z = __floats2half2_rn(accB.x, accB.y);
        *(__half2*)&r.w = __floats2half2_rn(accB.z, accB.w);
        ((uint4*)uout)[(size_t)node * 4 + lane] = r;
    }
}

extern "C" void kernel_launch(void* const* d_in, const int* in_sizes, int n_in,
                              void* d_out, int out_size, void* d_ws, size_t ws_size,
                              hipStream_t stream) {
    const float* feat = (const float*)d_in[0];
    const int*   src  = (const int*)d_in[1];
    const int*   dst  = (const int*)d_in[2];
    const float* W    = (const float*)d_in[3];
    const float* b    = (const float*)d_in[4];
    float* out = (float*)d_out;

    char* ws = (char*)d_ws;
    size_t off = 0;
    auto alloc = [&](size_t bytes) {
        void* p = ws + off;
        off = (off + bytes + 255) & ~(size_t)255;
        return p;
    };
    float*    norm   = (float*)alloc((size_t)NNODES * 4);
    unsigned* rowsd  = (unsigned*)alloc((size_t)NNODES * 4);
    int*      gcur   = (int*)alloc((size_t)NBUCK * 8 * CUR_PAD * 4);
    unsigned* packed = (unsigned*)alloc((size_t)NBUCK * PCAP * 4);
    int*      col    = (int*)alloc((size_t)NBUCK * PADCAP * 4);
    void*     h0     = alloc((size_t)(NNODES + 1) * OUTF * 2);   // fp16 + phantom
    void*     h1     = alloc((size_t)(NNODES + 1) * OUTF * 2);   // fp16 + phantom

    // ---- init sharded cursors + phantom rows; fused {binning || projection} ----
    k_initcur<<<13, 256, 0, stream>>>(gcur, (uint4*)h0, (uint4*)h1);
    k_binproj<<<BIN_BLOCKS + PROJ_BLOCKS, 256, 0, stream>>>(
        (const int4*)src, (const int4*)dst, gcur, packed,
        (const float4*)feat, (const float4*)W, (__half2*)h0);
    k_place<<<NBUCK, 256, 0, stream>>>(packed, gcur, col, rowsd, norm,
                                       (uint4*)h0);

    // ---- 4 uniform hops (u pre-scaled; w=norm^2 mid, norm+bias last) ----
    const int ggrid = (NNODES * 4 + 255) / 256;
    k_gather<false><<<ggrid, 256, 0, stream>>>(
        (const uint4*)h0, h1, rowsd, (const int4*)col, norm, nullptr);
    k_gather<false><<<ggrid, 256, 0, stream>>>(
        (const uint4*)h1, h0, rowsd, (const int4*)col, norm, nullptr);
    k_gather<false><<<ggrid, 256, 0, stream>>>(
        (const uint4*)h0, h1, rowsd, (const int4*)col, norm, nullptr);
    k_gather<true><<<ggrid, 256, 0, stream>>>(
        (const uint4*)h1, out, rowsd, (const int4*)col, norm, (const float4*)b);
}

// Round 20
// 116.121 us; speedup vs baseline: 1.0289x; 1.0289x over previous
//
#include <hip/hip_runtime.h>
#include <hip/hip_fp16.h>
#include <cstdint>

#define NNODES 100000
#define NEDGES 1200000
#define INF 64
#define OUTF 32
#define SCAN_B 256
#define NBUCK ((NNODES + SCAN_B - 1) / SCAN_B)   // 391; bucket b = dst >> 8
#define PCAP 4608                                 // packed slots/bucket
#define SHCAP 576                                 // slots per shard (8 shards/bucket)
#define PADCAP 5632                               // col slots/bucket (8-padded runs)
#define BIN_EPT 16
#define BIN_THREADS (NEDGES / BIN_EPT)            // 75000
#define BIN_BLOCKS ((BIN_THREADS + 255) / 256)    // 293
#define PROJ_NPB 16
#define PROJ_BLOCKS (NNODES / PROJ_NPB)           // 6250 (exact)
#define CUR_PAD 16                                // 64B-padded global cursors
#define WST 66                                    // proj LDS row stride (floats)

// ---- init: sharded cursors + phantom u-rows (row NNODES of h0/h1) ----
__global__ __launch_bounds__(256) void k_initcur(int* __restrict__ gcur,
                                                 uint4* __restrict__ h0,
                                                 uint4* __restrict__ h1) {
    int i = blockIdx.x * 256 + threadIdx.x;
    if (i < NBUCK * 8) gcur[i * CUR_PAD] = (i >> 3) * PCAP + (i & 7) * SHCAP;
    if (i >= 3200 && i < 3204) h0[(size_t)NNODES * 4 + (i - 3200)] = make_uint4(0, 0, 0, 0);
    if (i >= 3204 && i < 3208) h1[(size_t)NNODES * 4 + (i - 3204)] = make_uint4(0, 0, 0, 0);
}

// ---- fused: blocks [0,BIN_BLOCKS) bin edges; rest project h0 = X@W^T ----
// Phase-1 atomicAdd return IS the scatter slot: no second LDS-atomic pass.
__global__ __launch_bounds__(256) void k_binproj(const int4* __restrict__ src4,
                                                 const int4* __restrict__ dst4,
                                                 int* __restrict__ gcur,
                                                 unsigned* __restrict__ packed,
                                                 const float4* __restrict__ feat4,
                                                 const float4* __restrict__ W4,
                                                 __half2* __restrict__ h0_p) {
    __shared__ __align__(16) char smem[12672];
    int tid = threadIdx.x;
    if (blockIdx.x < BIN_BLOCKS) {
        int* cnt = (int*)smem;
        int* base = cnt + NBUCK;
        int shard = blockIdx.x & 7;
        for (int i = tid; i < NBUCK; i += 256) cnt[i] = 0;
        __syncthreads();
        int gid = blockIdx.x * 256 + tid;
        bool act = gid < BIN_THREADS;
        int4 s4[4], d4[4];
        int relv[4][4];
        if (act) {
#pragma unroll
            for (int k = 0; k < 4; ++k) {
                s4[k] = src4[(size_t)gid * 4 + k];
                d4[k] = dst4[(size_t)gid * 4 + k];
                relv[k][0] = atomicAdd(&cnt[d4[k].x >> 8], 1);
                relv[k][1] = atomicAdd(&cnt[d4[k].y >> 8], 1);
                relv[k][2] = atomicAdd(&cnt[d4[k].z >> 8], 1);
                relv[k][3] = atomicAdd(&cnt[d4[k].w >> 8], 1);
            }
        }
        __syncthreads();
        // reservation: shard-private cursor (R17) — cnt needs no reset
        for (int i = tid; i < NBUCK; i += 256) {
            int c = cnt[i];
            base[i] = c ? atomicAdd(&gcur[(i * 8 + shard) * CUR_PAD], c) : 0;
        }
        __syncthreads();
        if (act) {
#pragma unroll
            for (int k = 0; k < 4; ++k) {
                int ss[4] = {s4[k].x, s4[k].y, s4[k].z, s4[k].w};
                int dd[4] = {d4[k].x, d4[k].y, d4[k].z, d4[k].w};
#pragma unroll
                for (int j = 0; j < 4; ++j) {
                    int b = dd[j] >> 8;
                    packed[base[b] + relv[k][j]] =
                        ((unsigned)(dd[j] & 255) << 17) | (unsigned)ss[j];
                }
            }
        }
    } else {
        float (*Ws)[WST] = (float (*)[WST])smem;                    // [32][66]
        float (*Fs)[WST] = (float (*)[WST])(smem + 32 * WST * 4);   // [16][66]
        int node0 = (blockIdx.x - BIN_BLOCKS) * PROJ_NPB;
        for (int i = tid; i < 512; i += 256) {
            float4 w = W4[i];
            int f = i * 4, of = f >> 6, k = f & 63;
            Ws[of][k] = w.x; Ws[of][k + 1] = w.y;
            Ws[of][k + 2] = w.z; Ws[of][k + 3] = w.w;
        }
        {
            int n = node0 + (tid >> 4), q = tid & 15;
            float4 v = feat4[(size_t)n * 16 + q];
            int c = q * 4;
            Fs[tid >> 4][c] = v.x; Fs[tid >> 4][c + 1] = v.y;
            Fs[tid >> 4][c + 2] = v.z; Fs[tid >> 4][c + 3] = v.w;
        }
        __syncthreads();
        int ln = tid >> 4, n = node0 + ln;
        int of0 = (tid & 15) * 2;
        const float2* fp = (const float2*)&Fs[ln][0];
        const float2* w0 = (const float2*)&Ws[of0][0];
        const float2* w1 = (const float2*)&Ws[of0 + 1][0];
        float a0 = 0.0f, a1 = 0.0f;
#pragma unroll
        for (int k2 = 0; k2 < 32; ++k2) {
            float2 f = fp[k2], x = w0[k2], y = w1[k2];
            a0 += f.x * x.x + f.y * x.y;
            a1 += f.x * y.x + f.y * y.y;
        }
        h0_p[(size_t)n * 16 + (tid & 15)] = __floats2half2_rn(a0, a1);
    }
}

// ---- per bucket (512 threads): walk 8 shard sub-runs; degree (phase-1 rel
//      packed into bits 25..31), norm, 8-padded runs, atomic-free scatter,
//      col, rowsd, h0 *= norm epilogue ----
__global__ __launch_bounds__(512) void k_place(const unsigned* __restrict__ packed,
                                               const int* __restrict__ gcur,
                                               int* __restrict__ col,
                                               unsigned* __restrict__ rowsd,
                                               float* __restrict__ norm,
                                               uint4* __restrict__ h0) {
    __shared__ unsigned sin_[PCAP];
    __shared__ int stage[PADCAP];
    __shared__ int deg[SCAN_B];
    __shared__ int rs[SCAN_B];
    __shared__ int moff[SCAN_B];
    __shared__ int slen[8];
    __shared__ int tot;
    int b = blockIdx.x, tid = threadIdx.x;
    int node0 = b * SCAN_B;
    int nn = (NNODES - node0 < SCAN_B) ? (NNODES - node0) : SCAN_B;
    int ebase = b * PCAP;
    int pbase = b * PADCAP;
    if (tid < 8)
        slen[tid] = gcur[(b * 8 + tid) * CUR_PAD] - (b * PCAP + tid * SHCAP);
    if (tid < SCAN_B) deg[tid] = 0;
    __syncthreads();
    for (int s = 0; s < 8; ++s) {
        int len = slen[s];
        for (int i = tid; i < len; i += 512) {
            unsigned pk = packed[ebase + s * SHCAP + i];
            int r = atomicAdd(&deg[pk >> 17], 1);   // packed bits 25+ are 0
            sin_[s * SHCAP + i] = pk | ((unsigned)r << 25);  // rel < 128
        }
    }
    __syncthreads();
    int d = (tid < SCAN_B) ? deg[tid] : 0;
    int dpad = (d + 7) & ~7;
    if (tid < SCAN_B) rs[tid] = dpad;
    __syncthreads();
    for (int st = 1; st < SCAN_B; st <<= 1) {
        int add = (tid < SCAN_B && tid >= st) ? rs[tid - st] : 0;
        __syncthreads();
        if (tid < SCAN_B) rs[tid] += add;
        __syncthreads();
    }
    int myoff = (tid < SCAN_B) ? rs[tid] - dpad : 0;  // excl scan of padded deg
    if (tid == SCAN_B - 1) tot = rs[tid];
    float mynorm = rsqrtf(d < 1 ? 1.0f : (float)d);
    if (tid < nn) {
        norm[node0 + tid] = mynorm;
        rowsd[node0 + tid] =
            ((unsigned)((pbase + myoff) >> 3) << 9) | (unsigned)(dpad >> 3);
    }
    if (tid < SCAN_B) moff[tid] = myoff;
    __syncthreads();
    for (int i = tid; i < tot; i += 512) stage[i] = NNODES;  // phantom fill
    __syncthreads();
    for (int s = 0; s < 8; ++s) {
        int len = slen[s];
        for (int i = tid; i < len; i += 512) {
            unsigned pk = sin_[s * SHCAP + i];
            int dl = (pk >> 17) & 0xFF;
            int rel = (int)(pk >> 25);
            stage[moff[dl] + rel] = (int)(pk & 0x1FFFFu);   // no atomic
        }
    }
    __syncthreads();
    for (int i = tid; i < tot; i += 512) col[pbase + i] = stage[i];
    // epilogue: scale this bucket's h0 rows by norm (fp16 in/out, fp32 math)
    if (tid < nn) {
        uint4* hp = h0 + (size_t)(node0 + tid) * 4;
#pragma unroll
        for (int k = 0; k < 4; ++k) {
            uint4 r = hp[k];
            float2 f0 = __half22float2(*(const __half2*)&r.x);
            float2 f1 = __half22float2(*(const __half2*)&r.y);
            float2 f2 = __half22float2(*(const __half2*)&r.z);
            float2 f3 = __half22float2(*(const __half2*)&r.w);
            *(__half2*)&r.x = __floats2half2_rn(mynorm * f0.x, mynorm * f0.y);
            *(__half2*)&r.y = __floats2half2_rn(mynorm * f1.x, mynorm * f1.y);
            *(__half2*)&r.z = __floats2half2_rn(mynorm * f2.x, mynorm * f2.y);
            *(__half2*)&r.w = __floats2half2_rn(mynorm * f3.x, mynorm * f3.y);
            hp[k] = r;
        }
    }
}

// ---- one hop: uout[d] = w(d)*sum_e uin[col[e]]  (+bias) ----
// Runs are 8-padded: exact 8-edge rounds, int4 index loads, no tail.
// u rows: 32 fp16 = 64B; 4 lanes/node, uint4/lane. fp32 accum.
template <bool LAST>
__global__ __launch_bounds__(256) void k_gather(const uint4* __restrict__ uin,
                                                void* __restrict__ uout,
                                                const unsigned* __restrict__ rowsd,
                                                const int4* __restrict__ colv,
                                                const float* __restrict__ norm,
                                                const float4* __restrict__ bias4) {
    int t = blockIdx.x * 256 + threadIdx.x;
    int node = t >> 2;
    if (node >= NNODES) return;
    int lane = t & 3;
    unsigned rd = rowsd[node];
    int c4 = (int)(rd >> 9) * 2;      // int4 index of first col quad
    int n8 = (int)(rd & 511u);        // number of 8-edge rounds
    const uint4* up = uin + lane;
    float4 accA = make_float4(0.f, 0.f, 0.f, 0.f);
    float4 accB = make_float4(0.f, 0.f, 0.f, 0.f);
    auto add = [&](uint4 r) {
        float2 f0 = __half22float2(*(const __half2*)&r.x);
        float2 f1 = __half22float2(*(const __half2*)&r.y);
        float2 f2 = __half22float2(*(const __half2*)&r.z);
        float2 f3 = __half22float2(*(const __half2*)&r.w);
        accA.x += f0.x; accA.y += f0.y; accA.z += f1.x; accA.w += f1.y;
        accB.x += f2.x; accB.y += f2.y; accB.z += f3.x; accB.w += f3.y;
    };
    for (int j = 0; j < n8; ++j) {
        int4 c0 = colv[c4 + j * 2];
        int4 c1 = colv[c4 + j * 2 + 1];
        uint4 r0 = up[(size_t)c0.x * 4];
        uint4 r1 = up[(size_t)c0.y * 4];
        uint4 r2 = up[(size_t)c0.z * 4];
        uint4 r3 = up[(size_t)c0.w * 4];
        uint4 r4 = up[(size_t)c1.x * 4];
        uint4 r5 = up[(size_t)c1.y * 4];
        uint4 r6 = up[(size_t)c1.z * 4];
        uint4 r7 = up[(size_t)c1.w * 4];
        add(r0); add(r1); add(r2); add(r3);
        add(r4); add(r5); add(r6); add(r7);
    }
    float nn = norm[node];
    float w = LAST ? nn : nn * nn;
    accA.x *= w; accA.y *= w; accA.z *= w; accA.w *= w;
    accB.x *= w; accB.y *= w; accB.z *= w; accB.w *= w;
    if (LAST) {
        float4 b0 = bias4[lane * 2], b1 = bias4[lane * 2 + 1];
        accA.x += b0.x; accA.y += b0.y; accA.z += b0.z; accA.w += b0.w;
        accB.x += b1.x; accB.y += b1.y; accB.z += b1.z; accB.w += b1.w;
        float4* o = (float4*)uout;
        o[(size_t)node * 8 + lane * 2]     = accA;
        o[(size_t)node * 8 + lane * 2 + 1] = accB;
    } else {
        uint4 r;
        *(__half2*)&r.x = __floats2half2_rn(accA.x, accA.y);
        *(__half2*)&r.y = __floats2half2_rn(accA.z, accA.w);
        *(__half2*)&r.z = __floats2half2_rn(accB.x, accB.y);
        *(__half2*)&r.w = __floats2half2_rn(accB.z, accB.w);
        ((uint4*)uout)[(size_t)node * 4 + lane] = r;
    }
}

extern "C" void kernel_launch(void* const* d_in, const int* in_sizes, int n_in,
                              void* d_out, int out_size, void* d_ws, size_t ws_size,
                              hipStream_t stream) {
    const float* feat = (const float*)d_in[0];
    const int*   src  = (const int*)d_in[1];
    const int*   dst  = (const int*)d_in[2];
    const float* W    = (const float*)d_in[3];
    const float* b    = (const float*)d_in[4];
    float* out = (float*)d_out;

    char* ws = (char*)d_ws;
    size_t off = 0;
    auto alloc = [&](size_t bytes) {
        void* p = ws + off;
        off = (off + bytes + 255) & ~(size_t)255;
        return p;
    };
    float*    norm   = (float*)alloc((size_t)NNODES * 4);
    unsigned* rowsd  = (unsigned*)alloc((size_t)NNODES * 4);
    int*      gcur   = (int*)alloc((size_t)NBUCK * 8 * CUR_PAD * 4);
    unsigned* packed = (unsigned*)alloc((size_t)NBUCK * PCAP * 4);
    int*      col    = (int*)alloc((size_t)NBUCK * PADCAP * 4);
    void*     h0     = alloc((size_t)(NNODES + 1) * OUTF * 2);   // fp16 + phantom
    void*     h1     = alloc((size_t)(NNODES + 1) * OUTF * 2);   // fp16 + phantom

    // ---- init sharded cursors + phantom rows; fused {binning || projection} ----
    k_initcur<<<13, 256, 0, stream>>>(gcur, (uint4*)h0, (uint4*)h1);
    k_binproj<<<BIN_BLOCKS + PROJ_BLOCKS, 256, 0, stream>>>(
        (const int4*)src, (const int4*)dst, gcur, packed,
        (const float4*)feat, (const float4*)W, (__half2*)h0);
    k_place<<<NBUCK, 512, 0, stream>>>(packed, gcur, col, rowsd, norm,
                                       (uint4*)h0);

    // ---- 4 uniform hops (u pre-scaled; w=norm^2 mid, norm+bias last) ----
    const int ggrid = (NNODES * 4 + 255) / 256;
    k_gather<false><<<ggrid, 256, 0, stream>>>(
        (const uint4*)h0, h1, rowsd, (const int4*)col, norm, nullptr);
    k_gather<false><<<ggrid, 256, 0, stream>>>(
        (const uint4*)h1, h0, rowsd, (const int4*)col, norm, nullptr);
    k_gather<false><<<ggrid, 256, 0, stream>>>(
        (const uint4*)h0, h1, rowsd, (const int4*)col, norm, nullptr);
    k_gather<true><<<ggrid, 256, 0, stream>>>(
        (const uint4*)h1, out, rowsd, (const int4*)col, norm, (const float4*)b);
}